// Round 6
// baseline (231.277 us; speedup 1.0000x reference)
//
#include <hip/hip_runtime.h>
#include <hip/hip_bf16.h>

#define N_NODES 50000
#define N_EDGES 800000
#define IN_FEAT 256
#define UNITS   128

#define RANK_BLOCKS 3125           // ceil(800000/256)
#define GEMM_BLOCKS 782            // ceil(50000/64)

typedef unsigned short ushort_t;
typedef __bf16 bf16x8 __attribute__((ext_vector_type(8)));
typedef float  f32x4  __attribute__((ext_vector_type(4)));
typedef unsigned short ushort8 __attribute__((ext_vector_type(8)));

__device__ __forceinline__ ushort_t f2bf(float f) {
    unsigned u = __float_as_uint(f);
    u += 0x7fff + ((u >> 16) & 1);      // round-to-nearest-even
    return (ushort_t)(u >> 16);
}

// ---------------------------------------------------------------------------
// K0: Wt[n][k] = bf16(W[k][n]) AND zero counts[] (fused; runs every call).
// ---------------------------------------------------------------------------
__global__ __launch_bounds__(256) void prep_zero(const float* __restrict__ W,
                                                 ushort_t* __restrict__ Wt,
                                                 int* __restrict__ counts, int M) {
    int i = blockIdx.x * 256 + threadIdx.x;
    if (i < UNITS * IN_FEAT) {
        int n = i >> 8;
        int k = i & 255;
        Wt[i] = f2bf(W[(size_t)k * UNITS + n]);
    }
    if (i < M) counts[i] = 0;
}

// ---------------------------------------------------------------------------
// K_A (fused): blocks [0, RANK_BLOCKS) -> edge_rank (atomic-latency-bound),
//              blocks [RANK_BLOCKS, +GEMM_BLOCKS) -> MFMA gemm (compute).
// Independent inputs/outputs; co-scheduling hides atomic latency behind MFMA.
// ---------------------------------------------------------------------------
__global__ __launch_bounds__(256) void fusedA(const int* __restrict__ edges,
                                              int* __restrict__ counts,
                                              int* __restrict__ rank_, int E,
                                              const float* __restrict__ A,
                                              const ushort_t* __restrict__ Wt,
                                              ushort_t* __restrict__ Hb, int M) {
    const int bx  = blockIdx.x;
    const int tid = threadIdx.x;

    if (bx < RANK_BLOCKS) {
        // ---- edge_rank: rank[e] = arrival index among same-tgt edges ----
        int e = bx * 256 + tid;
        if (e < E) {
            int2 ts = ((const int2*)edges)[e];   // (tgt, src)
            rank_[e] = atomicAdd(&counts[ts.x], 1);
        }
        return;
    }

    // ---- gemm: h(bf16) = A @ W, MFMA 16x16x32, BM=64 BN=128 BK=32 ----
    __shared__ __align__(16) ushort_t As[64 * 40];    // 5 KB
    __shared__ __align__(16) ushort_t Bs[128 * 40];   // 10 KB
    const int lane = tid & 63;
    const int wv   = tid >> 6;
    const int wy   = wv >> 1;
    const int wx   = wv & 1;
    const int row0 = (bx - RANK_BLOCKS) * 64;
    const int quad = lane >> 4;
    const int cl   = lane & 15;

    f32x4 acc[2][4] = {};

    const int ar = tid >> 2, aq = tid & 3;
    const int gr = min(row0 + ar, M - 1);
    const float*    aptr   = A + (size_t)gr * IN_FEAT + aq * 8;
    ushort_t*       as_dst = As + ar * 40 + aq * 8;
    const int br = tid >> 1, bh = tid & 1;
    const ushort_t* wptr   = Wt + br * IN_FEAT + bh * 16;
    ushort_t*       bs_dst = Bs + br * 40 + bh * 16;

    for (int kc = 0; kc < IN_FEAT; kc += 32) {
        float4 f0 = *(const float4*)(aptr + kc);
        float4 f1 = *(const float4*)(aptr + kc + 4);
        ushort8 w0 = *(const ushort8*)(wptr + kc);
        ushort8 w1 = *(const ushort8*)(wptr + kc + 8);
        ushort8 u;
        u[0] = f2bf(f0.x); u[1] = f2bf(f0.y); u[2] = f2bf(f0.z); u[3] = f2bf(f0.w);
        u[4] = f2bf(f1.x); u[5] = f2bf(f1.y); u[6] = f2bf(f1.z); u[7] = f2bf(f1.w);
        __syncthreads();
        *(ushort8*)as_dst = u;
        *(ushort8*)bs_dst        = w0;
        *(ushort8*)(bs_dst + 8)  = w1;
        __syncthreads();

        bf16x8 af[2], bff[4];
#pragma unroll
        for (int mi = 0; mi < 2; ++mi)
            af[mi] = *(const bf16x8*)(As + (wy * 32 + mi * 16 + cl) * 40 + quad * 8);
#pragma unroll
        for (int ni = 0; ni < 4; ++ni)
            bff[ni] = *(const bf16x8*)(Bs + (wx * 64 + ni * 16 + cl) * 40 + quad * 8);
#pragma unroll
        for (int mi = 0; mi < 2; ++mi)
#pragma unroll
            for (int ni = 0; ni < 4; ++ni)
                acc[mi][ni] = __builtin_amdgcn_mfma_f32_16x16x32_bf16(
                    af[mi], bff[ni], acc[mi][ni], 0, 0, 0);
    }

#pragma unroll
    for (int mi = 0; mi < 2; ++mi) {
#pragma unroll
        for (int ni = 0; ni < 4; ++ni) {
            int col = wx * 64 + ni * 16 + cl;
#pragma unroll
            for (int r = 0; r < 4; ++r) {
                int row = row0 + wy * 32 + mi * 16 + quad * 4 + r;
                if (row < M)
                    Hb[(size_t)row * UNITS + col] = f2bf(acc[mi][ni][r]);
            }
        }
    }
}

// ---------------------------------------------------------------------------
// K_B (fused): block 0 -> single-block scan (counts -> offsets, exclusive),
//              blocks 1.. -> attn_dots (one wave per node).
// Independent: scan needs counts (from K_A rank), attn needs Hb (K_A gemm).
// ---------------------------------------------------------------------------
__global__ __launch_bounds__(256) void fusedB(const ushort_t* __restrict__ Hb,
                                              const float* __restrict__ ka,
                                              float* __restrict__ a_tgt,
                                              float* __restrict__ a_src,
                                              const int* __restrict__ counts,
                                              int* __restrict__ offsets, int M) {
    const int tid = threadIdx.x;

    if (blockIdx.x == 0) {
        // ---- scan: 256 threads x 32 contiguous elems = 8192/chunk, 7 chunks
        __shared__ int wsum[4];
        __shared__ int total_sh;
        const int lane = tid & 63, wv = tid >> 6;
        const int CH = 256 * 32;
        const int nch = (M + CH - 1) / CH;
        int base = 0;
        for (int ch = 0; ch < nch; ++ch) {
            int i0 = ch * CH + tid * 32;
            int a[32];
#pragma unroll
            for (int j = 0; j < 8; ++j) {
                int4 v = *(const int4*)(counts + i0 + j * 4);  // ws-safe OOB read
                a[j * 4 + 0] = v.x; a[j * 4 + 1] = v.y;
                a[j * 4 + 2] = v.z; a[j * 4 + 3] = v.w;
            }
            int run = 0;
#pragma unroll
            for (int k = 0; k < 32; ++k) {
                int val = (i0 + k < M) ? a[k] : 0;
                a[k] = run;                 // exclusive prefix within thread
                run += val;
            }
            int incl = run;
#pragma unroll
            for (int off = 1; off < 64; off <<= 1) {
                int t = __shfl_up(incl, off);
                if (lane >= off) incl += t;
            }
            if (lane == 63) wsum[wv] = incl;
            __syncthreads();
            if (tid == 0) {
                int r = 0;
#pragma unroll
                for (int i = 0; i < 4; ++i) { int x = wsum[i]; wsum[i] = r; r += x; }
                total_sh = r;
            }
            __syncthreads();
            int tb = base + wsum[wv] + (incl - run);
#pragma unroll
            for (int k = 0; k < 32; ++k)
                if (i0 + k < M) offsets[i0 + k] = tb + a[k];
            base += total_sh;
            __syncthreads();
        }
        if (tid == 0) offsets[M] = base;
        return;
    }

    // ---- attn_dots: wid = (bx-1)*4 + wave ----
    int wid  = (blockIdx.x - 1) * 4 + (tid >> 6);
    int lane = tid & 63;
    if (wid >= M) return;
    unsigned u = *(const unsigned*)(Hb + (size_t)wid * UNITS + lane * 2);
    float h0 = __uint_as_float(u << 16);
    float h1 = __uint_as_float(u & 0xffff0000u);
    float2 kt = *(const float2*)(ka + lane * 2);
    float2 ks = *(const float2*)(ka + UNITS + lane * 2);
    float pt = h0 * kt.x + h1 * kt.y;
    float ps = h0 * ks.x + h1 * ks.y;
#pragma unroll
    for (int off = 32; off > 0; off >>= 1) {
        pt += __shfl_down(pt, off);
        ps += __shfl_down(ps, off);
    }
    if (lane == 0) { a_tgt[wid] = pt; a_src[wid] = ps; }
}

__device__ __forceinline__ float edge_score(float at, float as) {
    float s = at + as;
    s = s > 0.f ? s : 0.2f * s;          // leaky_relu
    s = fminf(fmaxf(s, -2.f), 2.f);      // clip
    return __expf(s);
}

// ---------------------------------------------------------------------------
// K4: atomic-free CSR scatter; packed {src, score} int2 per entry.
// ---------------------------------------------------------------------------
__global__ __launch_bounds__(256) void build_csr(const int* __restrict__ edges,
                                                 const int* __restrict__ rank_,
                                                 const float* __restrict__ at,
                                                 const float* __restrict__ as,
                                                 const int* __restrict__ offsets,
                                                 int2* __restrict__ csr, int E) {
    int e = blockIdx.x * 256 + threadIdx.x;
    if (e >= E) return;
    int2 ts = ((const int2*)edges)[e];
    float sc = edge_score(at[ts.x], as[ts.y]);
    int pos = offsets[ts.x] + rank_[e];
    csr[pos] = make_int2(ts.y, __float_as_int(sc));
}

// ---------------------------------------------------------------------------
// K5: one wave per target node; 4 edge-slots x 16 feature-lanes.
// ---------------------------------------------------------------------------
__global__ __launch_bounds__(256) void aggregate(const ushort_t* __restrict__ Hb,
                                                 const int* __restrict__ offsets,
                                                 const int2* __restrict__ csr,
                                                 float* __restrict__ out, int M) {
    int wid  = (int)((blockIdx.x * 256 + threadIdx.x) >> 6);
    int lane = threadIdx.x & 63;
    if (wid >= M) return;
    const int g = lane >> 4;
    const int c = lane & 15;
    int beg = offsets[wid];
    int end = offsets[wid + 1];

    float acc[8] = {};
    float wacc = 0.f;

    for (int base = beg; base < end; base += 64) {
        int cd = min(64, end - base);
        int   s_v = 0;
        float w_v = 0.f;
        if (lane < cd) {
            int2 sw = csr[base + lane];
            s_v = sw.x;
            w_v = __int_as_float(sw.y);
        }
        wacc += w_v;
        int nstep = (cd + 3) >> 2;
#pragma unroll 4
        for (int t = 0; t < nstep; ++t) {
            int slot = t * 4 + g;
            int   src = __shfl(s_v, slot);
            float w   = __shfl(w_v, slot);
            uint4 u = *(const uint4*)(Hb + (size_t)src * UNITS + c * 8);
            acc[0] += w * __uint_as_float(u.x << 16);
            acc[1] += w * __uint_as_float(u.x & 0xffff0000u);
            acc[2] += w * __uint_as_float(u.y << 16);
            acc[3] += w * __uint_as_float(u.y & 0xffff0000u);
            acc[4] += w * __uint_as_float(u.z << 16);
            acc[5] += w * __uint_as_float(u.z & 0xffff0000u);
            acc[6] += w * __uint_as_float(u.w << 16);
            acc[7] += w * __uint_as_float(u.w & 0xffff0000u);
        }
    }

#pragma unroll
    for (int i = 0; i < 8; ++i) {
        acc[i] += __shfl_xor(acc[i], 16);
        acc[i] += __shfl_xor(acc[i], 32);
    }
#pragma unroll
    for (int off = 32; off > 0; off >>= 1) wacc += __shfl_xor(wacc, off);
    float scale = (end > beg) ? 1.0f / wacc : 0.0f;

    if (g == 0) {
        float4 o0 = make_float4(acc[0] * scale, acc[1] * scale,
                                acc[2] * scale, acc[3] * scale);
        float4 o1 = make_float4(acc[4] * scale, acc[5] * scale,
                                acc[6] * scale, acc[7] * scale);
        float* dst = out + (size_t)wid * UNITS + c * 8;
        *(float4*)dst       = o0;
        *(float4*)(dst + 4) = o1;
    }
}

// ---------------------------------------------------------------------------
extern "C" void kernel_launch(void* const* d_in, const int* in_sizes, int n_in,
                              void* d_out, int out_size, void* d_ws, size_t ws_size,
                              hipStream_t stream) {
    const float* node_states = (const float*)d_in[0];
    const int*   edges       = (const int*)d_in[1];   // int32 pairs (tgt,src)
    const float* W           = (const float*)d_in[2];
    const float* ka          = (const float*)d_in[3];
    float*       out         = (float*)d_out;

    const int M = N_NODES, E = N_EDGES;

    // workspace layout (no trailing backslashes in comments!)
    ushort_t* hb     = (ushort_t*)d_ws;                  // M*128 bf16 = 12.8 MB
    float*    a_tgt  = (float*)(hb + (size_t)M * UNITS); // M
    float*    a_src  = a_tgt + M;                        // M
    int*      counts = (int*)(a_src + M);                // M (zeroed in prep)
    int*      offsets= counts + M;                       // M+2
    int*      rank_  = offsets + M + 2;                  // E
    int2*     csr    = (int2*)(rank_ + E);               // E int2
    // Wt (64KB bf16) aliases csr storage: only used by prep_zero/fusedA,
    // which complete before build_csr writes csr. Stream-ordered => safe.
    ushort_t* wt     = (ushort_t*)csr;

    prep_zero <<<(M + 255) / 256, 256, 0, stream>>>(W, wt, counts, M);
    fusedA    <<<RANK_BLOCKS + GEMM_BLOCKS, 256, 0, stream>>>(edges, counts, rank_, E,
                                                              node_states, wt, hb, M);
    fusedB    <<<1 + (M + 3) / 4, 256, 0, stream>>>(hb, ka, a_tgt, a_src,
                                                    counts, offsets, M);
    build_csr <<<(E + 255) / 256, 256, 0, stream>>>(edges, rank_, a_tgt, a_src,
                                                    offsets, csr, E);
    aggregate <<<(M * 64 + 255) / 256, 256, 0, stream>>>(hb, offsets, csr, out, M);
}